// Round 1
// baseline (353.389 us; speedup 1.0000x reference)
//
#include <hip/hip_runtime.h>
#include <hip/hip_bf16.h>

// out[b,k,oc,x] = sum_i W[k,oc,i] * in[b,i,k,x] + bias[k,oc]
// B=4096, Cin=Cout=128, K(offsets)=9, X=9.
// Memory-bound (340 MB min traffic ~54us); bf16 MFMA makes compute ~4.6us.

#define NB   4096
#define CINC 128
#define COUTC 128
#define NK   9
#define NX   9
#define BT   16               // b's per workgroup
#define NCOL (BT * NX)        // 144 columns per workgroup
#define LDK  136              // padded row length (shorts): 128 + 8 -> 16B-aligned rows, 2-way-max bank alias

typedef __attribute__((ext_vector_type(8))) short short8;
typedef __attribute__((ext_vector_type(4))) float floatx4;

__device__ __forceinline__ short f2bf(float f) {
    union { float f; unsigned u; } v; v.f = f;
    unsigned r = v.u + 0x7fff + ((v.u >> 16) & 1);  // RNE; inputs are finite normals
    return (short)(r >> 16);
}

__global__ __launch_bounds__(512, 4) void GatherVertical_40656160424516_kernel(
    const float* __restrict__ in, const float* __restrict__ w,
    const float* __restrict__ bias, float* __restrict__ out)
{
    __shared__ short Wl[COUTC * LDK];   // [oc][i] bf16, 34816 B
    __shared__ short Il[NCOL * LDK];    // [nx][i] bf16, 39168 B  (total ~74 KB -> 2 blk/CU)

    const int t = threadIdx.x;
    const int k = blockIdx.x % NK;        // btile-major order: 9 k-siblings adjacent -> L3 line sharing
    const int btile = blockIdx.x / NK;
    const int b0 = btile * BT;

    // ---- stage W_k: weights[k][oc][i] f32 (i contiguous) -> bf16 LDS [oc][i]
    const float* wk = w + k * (COUTC * CINC);
    #pragma unroll
    for (int it = 0; it < 8; ++it) {
        int idx4 = it * 512 + t;                 // 0..4095 float4s
        int flat = idx4 * 4;
        int oc = flat >> 7;
        int i  = flat & 127;
        float4 v = *(const float4*)(wk + flat);
        short4 s;
        s.x = f2bf(v.x); s.y = f2bf(v.y); s.z = f2bf(v.z); s.w = f2bf(v.w);
        *(short4*)&Wl[oc * LDK + i] = s;
    }

    // ---- stage input tile: in[b0+bl, i, k, x] -> Il[bl*9+x][i]
    // global order: x fastest, then i, then bl -> 36B contiguous segments, coalesced within segments
    const float* inb = in + (size_t)b0 * (CINC * NK * NX) + k * NX;
    #pragma unroll
    for (int it = 0; it < 36; ++it) {
        int f = it * 512 + t;                    // 0..18431
        int bl = f / (CINC * NX);                // /1152 (magic mul)
        int rem = f - bl * (CINC * NX);
        int i = rem / NX;
        int x = rem - i * NX;
        float v = inb[bl * (CINC * NK * NX) + i * (NK * NX) + x];
        Il[(bl * NX + x) * LDK + i] = f2bf(v);
    }

    __syncthreads();

    const int lane = t & 63;
    const int wv = t >> 6;                       // 0..7: wave's M-tile (16 oc rows)
    const int lc = lane & 15;
    const int quad = lane >> 4;

    floatx4 acc[9];
    #pragma unroll
    for (int n = 0; n < 9; ++n) acc[n] = (floatx4){0.f, 0.f, 0.f, 0.f};

    const int oc_base = wv * 16;
    // A-frag: A[m=lane&15][kk=quad*8+j] from Wl; B-frag: B[kk][n=lane&15] read as Il[n][kk..kk+7]
    #pragma unroll
    for (int s = 0; s < 4; ++s) {
        int kof = s * 32 + quad * 8;
        short8 a = *(const short8*)&Wl[(oc_base + lc) * LDK + kof];
        #pragma unroll
        for (int n = 0; n < 9; ++n) {
            short8 bfr = *(const short8*)&Il[(n * 16 + lc) * LDK + kof];
            acc[n] = __builtin_amdgcn_mfma_f32_16x16x32_bf16(a, bfr, acc[n], 0, 0, 0);
        }
    }

    // ---- bias for this lane's 4 oc rows (row = quad*4 + reg)
    const float* bk = bias + k * COUTC;
    float bsv[4];
    #pragma unroll
    for (int r = 0; r < 4; ++r) bsv[r] = bk[oc_base + quad * 4 + r];

    // ---- store: out[b, k, oc, x]; C/D: col(lane&15)=nx, row(quad*4+r)=oc
    #pragma unroll
    for (int n = 0; n < 9; ++n) {
        int nx = n * 16 + lc;
        int bl = nx / 9;
        int x = nx - bl * 9;
        float* op = out + (size_t)(b0 + bl) * (NK * COUTC * NX) + k * (COUTC * NX)
                        + (oc_base + quad * 4) * NX + x;
        #pragma unroll
        for (int r = 0; r < 4; ++r)
            op[r * NX] = acc[n][r] + bsv[r];
    }
}

extern "C" void kernel_launch(void* const* d_in, const int* in_sizes, int n_in,
                              void* d_out, int out_size, void* d_ws, size_t ws_size,
                              hipStream_t stream) {
    const float* in  = (const float*)d_in[0];
    const float* w   = (const float*)d_in[1];
    const float* bs  = (const float*)d_in[2];
    float* out = (float*)d_out;
    dim3 grid((NB / BT) * NK);   // 2304 blocks, btile-major
    dim3 block(512);
    GatherVertical_40656160424516_kernel<<<grid, block, 0, stream>>>(in, w, bs, out);
}

// Round 2
// 352.741 us; speedup vs baseline: 1.0018x; 1.0018x over previous
//
#include <hip/hip_runtime.h>
#include <hip/hip_bf16.h>

// out[b,k,oc,x] = sum_i W[k,oc,i] * in[b,i,k,x] + bias[k,oc]
// B=4096, Cin=Cout=128, K(offsets)=9, X=9.
// Memory-bound: 340 MB min traffic ~54us @6.3TB/s. bf16 MFMA compute ~4.6us.
// R1: XCD-aware swizzle so the 9 k-siblings of a btile co-run on ONE XCD
//     (shared L2 -> input lines fetched once, kills the 2.1x over-fetch);
//     W read direct from global (L2-resident) instead of LDS staging.

#define NB   4096
#define CINC 128
#define COUTC 128
#define NK   9
#define NX   9
#define BT   16               // b's per workgroup
#define NCOL (BT * NX)        // 144 columns per workgroup
#define LDK  136              // padded row length (shorts): 16B-aligned rows, 2-way-max bank alias

typedef __attribute__((ext_vector_type(8))) short short8;
typedef __attribute__((ext_vector_type(4))) float floatx4;

__device__ __forceinline__ short f2bf(float f) {
    union { float f; unsigned u; } v; v.f = f;
    unsigned r = v.u + 0x7fff + ((v.u >> 16) & 1);  // RNE; inputs are finite normals
    return (short)(r >> 16);
}

__global__ __launch_bounds__(512, 6) void GatherVertical_40656160424516_kernel(
    const float* __restrict__ in, const float* __restrict__ w,
    const float* __restrict__ bias, float* __restrict__ out)
{
    __shared__ short Il[NCOL * LDK];    // [nx][i] bf16, 39168 B -> LDS allows 4 blk/CU

    const int t = threadIdx.x;

    // ---- XCD swizzle: siblings (same btile, k=0..8) land on the same XCD,
    // adjacent in that XCD's dispatch stream.
    const int j = blockIdx.x;
    const int xcd = j & 7;
    const int slot = j >> 3;          // 0..287 per XCD
    const int grp = slot / 9;         // 0..31
    const int k = slot - grp * 9;     // 0..8
    const int btile = grp * 8 + xcd;  // 0..255
    const int b0 = btile * BT;

    const int lane = t & 63;
    const int wv = t >> 6;            // 0..7: wave's M-tile (16 oc rows)
    const int lc = lane & 15;
    const int quad = lane >> 4;
    const int oc_base = wv * 16;

    // ---- A-fragments direct from global (L2-hit; same data for all 256 btiles).
    // A[m=lane&15][kk=quad*8+j], four K-steps of 32.
    const float* wk = w + k * (COUTC * CINC);
    short8 afr[4];
    #pragma unroll
    for (int s = 0; s < 4; ++s) {
        const float* wp = wk + (oc_base + lc) * CINC + s * 32 + quad * 8;
        float4 w0 = *(const float4*)wp;
        float4 w1 = *(const float4*)(wp + 4);
        short8 a;
        a[0] = f2bf(w0.x); a[1] = f2bf(w0.y); a[2] = f2bf(w0.z); a[3] = f2bf(w0.w);
        a[4] = f2bf(w1.x); a[5] = f2bf(w1.y); a[6] = f2bf(w1.z); a[7] = f2bf(w1.w);
        afr[s] = a;
    }

    // ---- bias for this lane's 4 oc rows (row = quad*4 + reg)
    const float* bk = bias + k * COUTC;
    float bsv[4];
    #pragma unroll
    for (int r = 0; r < 4; ++r) bsv[r] = bk[oc_base + quad * 4 + r];

    // ---- stage input tile: in[b0+bl, i, k, x] -> Il[bl*9+x][i]
    // x fastest across threads -> wave reads 256B contiguous (2 full lines/instr)
    const float* inb = in + (size_t)b0 * (CINC * NK * NX) + k * NX;
    #pragma unroll
    for (int it = 0; it < 36; ++it) {
        int f = it * 512 + t;                    // 0..18431
        int bl = f / (CINC * NX);                // /1152 (magic mul)
        int rem = f - bl * (CINC * NX);
        int i = rem / NX;
        int x = rem - i * NX;
        float v = inb[bl * (CINC * NK * NX) + i * (NK * NX) + x];
        Il[(bl * NX + x) * LDK + i] = f2bf(v);
    }

    __syncthreads();

    floatx4 acc[9];
    #pragma unroll
    for (int n = 0; n < 9; ++n) acc[n] = (floatx4){0.f, 0.f, 0.f, 0.f};

    // B-frag: B[kk][n=lane&15] read as Il[n][kk..kk+7]
    #pragma unroll
    for (int s = 0; s < 4; ++s) {
        int kof = s * 32 + quad * 8;
        #pragma unroll
        for (int n = 0; n < 9; ++n) {
            short8 bfr = *(const short8*)&Il[(n * 16 + lc) * LDK + kof];
            acc[n] = __builtin_amdgcn_mfma_f32_16x16x32_bf16(afr[s], bfr, acc[n], 0, 0, 0);
        }
    }

    // ---- store: out[b, k, oc, x]; C/D: col(lane&15)=nx, row(quad*4+r)=oc
    #pragma unroll
    for (int n = 0; n < 9; ++n) {
        int nx = n * 16 + lc;
        int bl = nx / 9;
        int x = nx - bl * 9;
        float* op = out + (size_t)(b0 + bl) * (NK * COUTC * NX) + k * (COUTC * NX)
                        + (oc_base + quad * 4) * NX + x;
        #pragma unroll
        for (int r = 0; r < 4; ++r)
            op[r * NX] = acc[n][r] + bsv[r];
    }
}

extern "C" void kernel_launch(void* const* d_in, const int* in_sizes, int n_in,
                              void* d_out, int out_size, void* d_ws, size_t ws_size,
                              hipStream_t stream) {
    const float* in  = (const float*)d_in[0];
    const float* w   = (const float*)d_in[1];
    const float* bs  = (const float*)d_in[2];
    float* out = (float*)d_out;
    dim3 grid((NB / BT) * NK);   // 2304 blocks, XCD-swizzled in-kernel
    dim3 block(512);
    GatherVertical_40656160424516_kernel<<<grid, block, 0, stream>>>(in, w, bs, out);
}